// Round 14
// baseline (130.724 us; speedup 1.0000x reference)
//
#include <hip/hip_runtime.h>
#include <hip/hip_bf16.h>

#define HH 1024
#define LL 512
#define NT 16              // 512/32 row-tiles
#define NTRI 136           // NT*(NT+1)/2 triangular tiles

typedef __attribute__((ext_vector_type(8))) short bf16x8;
typedef __attribute__((ext_vector_type(4))) float f32x4;
typedef __attribute__((ext_vector_type(2))) float f32x2;

static constexpr float C_EXP = 2.8853900817779268f; // 2*log2(e)

// pack 8 fp32 -> 8 bf16 (RNE) as uint4
static __device__ __forceinline__ uint4 pack8(float4 a, float4 b) {
    union { uint4 u; __hip_bfloat162 h[4]; } r;
    r.h[0] = __float22bfloat162_rn(make_float2(a.x, a.y));
    r.h[1] = __float22bfloat162_rn(make_float2(a.z, a.w));
    r.h[2] = __float22bfloat162_rn(make_float2(b.x, b.y));
    r.h[3] = __float22bfloat162_rn(make_float2(b.z, b.w));
    return r.u;
}

// ---------------------------------------------------------------------------
// Kernel 1: bf16 MFMA projection, fp32->bf16 fused into staging (R12 form).
// Tile 64m x 64n, BK=128, grid 256, XCD swizzle.
//   n < 1024:  Ea[m][n] = exp2(C*(acc+b1[n]));  else Eb[m][n-1024] = exp2(C*acc)
// ---------------------------------------------------------------------------
__global__ __launch_bounds__(256, 4) void proj_mfma_kernel(
    const float* __restrict__ lm, const float* __restrict__ W1,
    const float* __restrict__ b1, float* __restrict__ Ea, float* __restrict__ Eb)
{
    __shared__ ushort As[64][136];  // 136 us = 68 dw = 4 mod 32 banks: <=2-way, free
    __shared__ ushort Bs[64][136];

    const int tid  = threadIdx.x;
    const int lane = tid & 63;
    const int w    = tid >> 6;
    const int b    = blockIdx.x;          // 0..255
    const int xcd  = b & 7;
    const int idx  = b >> 3;              // 0..31
    const int nbase = (xcd * 4 + (idx & 3)) * 64;   // 0..2047
    const int mbase = (idx >> 2) * 64;              // 0..448
    const int wm   = w * 16;
    const int sel  = nbase >> 10;         // block-uniform: Wa(0)/Wb(1)
    const int nrow = nbase & 1023;

    const int frow = lane & 15;
    const int q8   = (lane >> 4) * 8;

    f32x4 acc[4] = {};

    for (int kb = 0; kb < HH; kb += 128) {
        __syncthreads();
        {
            int p = tid;
#pragma unroll
            for (int it = 0; it < 4; ++it, p += 256) {
                const int row = p >> 4, c8 = (p & 15) * 8;
                const float* pa = &lm[(mbase + row) * HH + kb + c8];
                *(uint4*)&As[row][c8] = pack8(*(const float4*)pa, *(const float4*)(pa + 4));
                const float* pw = &W1[(nrow + row) * 2048 + sel * 1024 + kb + c8];
                *(uint4*)&Bs[row][c8] = pack8(*(const float4*)pw, *(const float4*)(pw + 4));
            }
        }
        __syncthreads();

#pragma unroll
        for (int s = 0; s < 4; ++s) {
            const bf16x8 a = *(const bf16x8*)&As[wm + frow][s * 32 + q8];
#pragma unroll
            for (int nf = 0; nf < 4; ++nf) {
                const bf16x8 bb = *(const bf16x8*)&Bs[nf * 16 + frow][s * 32 + q8];
                acc[nf] = __builtin_amdgcn_mfma_f32_16x16x32_bf16(a, bb, acc[nf], 0, 0, 0);
            }
        }
    }

    // D mapping: col=lane&15 (n), row=(lane>>4)*4+reg (m)
    const int col = lane & 15;
    const int rq  = (lane >> 4) * 4;
    const int m0  = mbase + wm + rq;
    const bool isA = sel == 0;            // block-uniform
#pragma unroll
    for (int nf = 0; nf < 4; ++nf) {
        const int nn = (nrow + nf * 16 + col);
        if (isA) {
            const float bb = b1[nn];
#pragma unroll
            for (int r = 0; r < 4; ++r)
                Ea[(m0 + r) * HH + nn] = __builtin_amdgcn_exp2f(C_EXP * (acc[nf][r] + bb));
        } else {
#pragma unroll
            for (int r = 0; r < 4; ++r)
                Eb[(m0 + r) * HH + nn] = __builtin_amdgcn_exp2f(C_EXP * acc[nf][r]);
        }
    }
}

// ---------------------------------------------------------------------------
// Kernel 2: triangular pairwise contraction. Keeps R13's wins (W2 via wave-
// uniform scalar loads; jj-packed f32x2 accumulators) but reverts the XOR
// swizzle (measured +2.2M conflicts) to the proven padding: tx-indexed tiles
// (Ea[j], Eb[j]) at stride 68 (bank-group (17*tx+h4)%8 -> 2-way = free);
// ty-indexed tiles at stride 64 (broadcast reads: conflict-immune).
// LDS = 33792 B -> 4 blocks/CU.
// ---------------------------------------------------------------------------
__global__ __launch_bounds__(256, 4) void pair_kernel(
    const float* __restrict__ Ea, const float* __restrict__ Eb,
    const float* __restrict__ W2, float* __restrict__ pbuf, int slice)
{
    __shared__ float eaj[32][68];   // tx-read: padded
    __shared__ float ebj[32][68];   // tx-read: padded
    __shared__ float eai[32][64];   // ty-read: broadcast, unpadded
    __shared__ float ebi[32][64];   // ty-read: broadcast, unpadded

    const int tid = threadIdx.x;
    const int tx  = tid & 15;
    const int ty  = tid >> 4;         // 0..15

    int tt = blockIdx.x, bi = 0, rem = NT;          // triangular decode
    while (tt >= rem) { tt -= rem; --rem; ++bi; }
    const int bj    = bi + tt;
    const int ibase = bi * 32;
    const int jbase = bj * 32;
    const int k0    = blockIdx.y * slice;

    f32x2 aC0[2] = {}, aC1[2] = {};   // [ii], packed over jj
    const f32x2 one2 = {1.f, 1.f};

    for (int kb = 0; kb < slice; kb += 64) {
        if (kb) __syncthreads();
        {   // stage 4 tiles x 32 rows x 64 floats = 2048 float4, 8/thread
            int p = tid;
#pragma unroll
            for (int it = 0; it < 8; ++it, p += 256) {
                const int tile = p >> 9;             // compile-time per it
                const int row  = (p >> 4) & 31;
                const int c4   = p & 15;
                if (tile == 0) {
                    const float4 v = *(const float4*)&Ea[(jbase + row) * HH + k0 + kb + c4 * 4];
                    *(float4*)&eaj[row][c4 * 4] = v;
                } else if (tile == 1) {
                    const float4 v = *(const float4*)&Ea[(ibase + row) * HH + k0 + kb + c4 * 4];
                    *(float4*)&eai[row][c4 * 4] = v;
                } else if (tile == 2) {
                    const float4 v = *(const float4*)&Eb[(ibase + row) * HH + k0 + kb + c4 * 4];
                    *(float4*)&ebi[row][c4 * 4] = v;
                } else {
                    const float4 v = *(const float4*)&Eb[(jbase + row) * HH + k0 + kb + c4 * 4];
                    *(float4*)&ebj[row][c4 * 4] = v;
                }
            }
        }
        __syncthreads();

#pragma unroll 4
        for (int h4 = 0; h4 < 16; ++h4) {
            const float4 Aj0 = *(const float4*)&eaj[tx][h4 * 4];
            const float4 Aj1 = *(const float4*)&eaj[tx + 16][h4 * 4];
            const float4 Bj0 = *(const float4*)&ebj[tx][h4 * 4];
            const float4 Bj1 = *(const float4*)&ebj[tx + 16][h4 * 4];
            const float4 Ai0 = *(const float4*)&eai[ty][h4 * 4];
            const float4 Ai1 = *(const float4*)&eai[ty + 16][h4 * 4];
            const float4 Bi0 = *(const float4*)&ebi[ty][h4 * 4];
            const float4 Bi1 = *(const float4*)&ebi[ty + 16][h4 * 4];
            const float4 w0q = *(const float4*)&W2[k0 + kb + h4 * 4];      // uniform -> scalar
            const float4 w1q = *(const float4*)&W2[HH + k0 + kb + h4 * 4];

#define DO_H(AJ0v, AJ1v, BI0v, BI1v, AI0v, AI1v, BJ0v, BJ1v, W0s, W1s)        \
            {                                                                  \
                const f32x2 Aj = {AJ0v, AJ1v};                                 \
                const f32x2 Bj = {BJ0v, BJ1v};                                 \
                const f32x2 d0 = __builtin_elementwise_fma((f32x2){BI0v, BI0v}, Aj, one2); \
                const f32x2 d1 = __builtin_elementwise_fma((f32x2){BI1v, BI1v}, Aj, one2); \
                const f32x2 e0 = __builtin_elementwise_fma((f32x2){AI0v, AI0v}, Bj, one2); \
                const f32x2 e1 = __builtin_elementwise_fma((f32x2){AI1v, AI1v}, Bj, one2); \
                const float dp0 = d0.x * d0.y, dp1 = d1.x * d1.y;              \
                const float ep0 = e0.x * e0.y, ep1 = e1.x * e1.y;              \
                const float DR = __builtin_amdgcn_rcpf(dp0 * dp1);             \
                const float ER = __builtin_amdgcn_rcpf(ep0 * ep1);             \
                const f32x2 dq = (f32x2){DR, DR} * (f32x2){dp1, dp0};          \
                const f32x2 eq = (f32x2){ER, ER} * (f32x2){ep1, ep0};          \
                const f32x2 u0 = (f32x2){dq.x, dq.x} * d0.yx + (f32x2){eq.x, eq.x} * e0.yx; \
                const f32x2 u1 = (f32x2){dq.y, dq.y} * d1.yx + (f32x2){eq.y, eq.y} * e1.yx; \
                aC0[0] = __builtin_elementwise_fma(u0, (f32x2){(W0s), (W0s)}, aC0[0]); \
                aC1[0] = __builtin_elementwise_fma(u0, (f32x2){(W1s), (W1s)}, aC1[0]); \
                aC0[1] = __builtin_elementwise_fma(u1, (f32x2){(W0s), (W0s)}, aC0[1]); \
                aC1[1] = __builtin_elementwise_fma(u1, (f32x2){(W1s), (W1s)}, aC1[1]); \
            }
            DO_H(Aj0.x, Aj1.x, Bi0.x, Bi1.x, Ai0.x, Ai1.x, Bj0.x, Bj1.x, w0q.x, w1q.x)
            DO_H(Aj0.y, Aj1.y, Bi0.y, Bi1.y, Ai0.y, Ai1.y, Bj0.y, Bj1.y, w0q.y, w1q.y)
            DO_H(Aj0.z, Aj1.z, Bi0.z, Bi1.z, Ai0.z, Ai1.z, Bj0.z, Bj1.z, w0q.z, w1q.z)
            DO_H(Aj0.w, Aj1.w, Bi0.w, Bi1.w, Ai0.w, Ai1.w, Bj0.w, Bj1.w, w0q.w, w1q.w)
#undef DO_H
        }
    }

    // value(ii,jj,c) = (c ? aC1 : aC0)[ii][jj]
    float* pb = pbuf + ((size_t)blockIdx.y * NTRI + blockIdx.x) * 2048;
#pragma unroll
    for (int ii = 0; ii < 2; ++ii)
#pragma unroll
        for (int jj = 0; jj < 2; ++jj) {
            const int li = ty + ii * 16, lj = tx + jj * 16;
            const f32x2 v = { jj ? aC0[ii].y : aC0[ii].x,
                              jj ? aC1[ii].y : aC1[ii].x };
            *(f32x2*)&pb[(li * 32 + lj) * 2] = v;
        }
}

// ---------------------------------------------------------------------------
// Kernel 3: combine: out = wsum[c]+b2[c] - sum_z pbuf; scatter (i,j)+(j,i).
// 1088 blocks, 2-way ILP on z.
// ---------------------------------------------------------------------------
__global__ __launch_bounds__(256) void combine_kernel(
    const float* __restrict__ pbuf, const float* __restrict__ W2,
    const float* __restrict__ b2, float* __restrict__ out, int nz)
{
    __shared__ float s_ws[2];

    const int tid = threadIdx.x;
    if (tid < 128) {
        const int c = tid >> 6, l = tid & 63;
        float s = 0.f;
#pragma unroll
        for (int q = 0; q < 4; ++q) {
            const float4 v = *(const float4*)&W2[c * HH + (l + q * 64) * 4];
            s += v.x + v.y + v.z + v.w;
        }
#pragma unroll
        for (int off = 32; off; off >>= 1) s += __shfl_down(s, off, 64);
        if (l == 0) s_ws[c] = s + b2[c];
    }
    __syncthreads();

    const int idx   = blockIdx.x * 256 + tid;   // 0 .. 136*2048-1
    const int t     = idx >> 11;                // block-uniform
    const int local = idx & 2047;
    int tt = t, bi = 0, rem = NT;
    while (tt >= rem) { tt -= rem; --rem; ++bi; }
    const int bj = bi + tt;

    float s0 = 0.f, s1 = 0.f;
    for (int z = 0; z < nz; z += 2) {   // nz is even
        s0 += pbuf[((size_t)z * NTRI + t) * 2048 + local];
        s1 += pbuf[((size_t)(z + 1) * NTRI + t) * 2048 + local];
    }
    const float s = s0 + s1;

    const int li = local >> 6;
    const int lj = (local >> 1) & 31;
    const int c  = local & 1;
    const float v = s_ws[c] - s;

    const int i = bi * 32 + li;
    const int j = bj * 32 + lj;
    out[(i * LL + j) * 2 + c] = v;
    out[(j * LL + i) * 2 + c] = v;   // diagonal tiles: same-value rewrite, benign
}

extern "C" void kernel_launch(void* const* d_in, const int* in_sizes, int n_in,
                              void* d_out, int out_size, void* d_ws, size_t ws_size,
                              hipStream_t stream)
{
    const float* lm = (const float*)d_in[0];
    const float* W1 = (const float*)d_in[1];
    const float* b1 = (const float*)d_in[2];
    const float* W2 = (const float*)d_in[3];
    const float* b2 = (const float*)d_in[4];
    float* out = (float*)d_out;

    char* ws = (char*)d_ws;
    float* Ea   = (float*)ws;                            // 2 MB
    float* Eb   = (float*)(ws + (2u << 20));             // 2 MB
    float* pbuf = (float*)(ws + (4u << 20) + 64);        // nz * 1.11 MB

    const size_t ubase = (4u << 20) + 64;
    const size_t pb16  = (size_t)16 * NTRI * 2048 * 4;   // 17.8 MB
    const int nz = (ws_size >= ubase + pb16) ? 16 : 8;   // ws_size const/session
    const int slice = HH / nz;

    proj_mfma_kernel<<<256, 256, 0, stream>>>(lm, W1, b1, Ea, Eb);
    pair_kernel<<<dim3(NTRI, nz), 256, 0, stream>>>(Ea, Eb, W2, pbuf, slice);
    combine_kernel<<<(NTRI * 2048) / 256, 256, 0, stream>>>(pbuf, W2, b2, out, nz);
}

// Round 15
// 129.457 us; speedup vs baseline: 1.0098x; 1.0098x over previous
//
#include <hip/hip_runtime.h>
#include <hip/hip_bf16.h>

#define HH 1024
#define LL 512
#define NT 16              // 512/32 row-tiles
#define NTRI 136           // NT*(NT+1)/2 triangular tiles

typedef __attribute__((ext_vector_type(8))) short bf16x8;
typedef __attribute__((ext_vector_type(4))) float f32x4;
typedef __attribute__((ext_vector_type(2))) float f32x2;

static constexpr float C_EXP = 2.8853900817779268f; // 2*log2(e)

// pack 8 fp32 -> 8 bf16 (RNE) as uint4
static __device__ __forceinline__ uint4 pack8(float4 a, float4 b) {
    union { uint4 u; __hip_bfloat162 h[4]; } r;
    r.h[0] = __float22bfloat162_rn(make_float2(a.x, a.y));
    r.h[1] = __float22bfloat162_rn(make_float2(a.z, a.w));
    r.h[2] = __float22bfloat162_rn(make_float2(b.x, b.y));
    r.h[3] = __float22bfloat162_rn(make_float2(b.z, b.w));
    return r.u;
}

// ---------------------------------------------------------------------------
// Kernel 1: bf16 MFMA projection, fp32->bf16 fused into staging (R12 form).
// Tile 64m x 64n, BK=128, grid 256, XCD swizzle.
//   n < 1024:  Ea[m][n] = exp2(C*(acc+b1[n]));  else Eb[m][n-1024] = exp2(C*acc)
// ---------------------------------------------------------------------------
__global__ __launch_bounds__(256, 4) void proj_mfma_kernel(
    const float* __restrict__ lm, const float* __restrict__ W1,
    const float* __restrict__ b1, float* __restrict__ Ea, float* __restrict__ Eb)
{
    __shared__ ushort As[64][136];  // 136 us = 68 dw = 4 mod 32 banks: <=2-way, free
    __shared__ ushort Bs[64][136];

    const int tid  = threadIdx.x;
    const int lane = tid & 63;
    const int w    = tid >> 6;
    const int b    = blockIdx.x;          // 0..255
    const int xcd  = b & 7;
    const int idx  = b >> 3;              // 0..31
    const int nbase = (xcd * 4 + (idx & 3)) * 64;   // 0..2047
    const int mbase = (idx >> 2) * 64;              // 0..448
    const int wm   = w * 16;
    const int sel  = nbase >> 10;         // block-uniform: Wa(0)/Wb(1)
    const int nrow = nbase & 1023;

    const int frow = lane & 15;
    const int q8   = (lane >> 4) * 8;

    f32x4 acc[4] = {};

    for (int kb = 0; kb < HH; kb += 128) {
        __syncthreads();
        {
            int p = tid;
#pragma unroll
            for (int it = 0; it < 4; ++it, p += 256) {
                const int row = p >> 4, c8 = (p & 15) * 8;
                const float* pa = &lm[(mbase + row) * HH + kb + c8];
                *(uint4*)&As[row][c8] = pack8(*(const float4*)pa, *(const float4*)(pa + 4));
                const float* pw = &W1[(nrow + row) * 2048 + sel * 1024 + kb + c8];
                *(uint4*)&Bs[row][c8] = pack8(*(const float4*)pw, *(const float4*)(pw + 4));
            }
        }
        __syncthreads();

#pragma unroll
        for (int s = 0; s < 4; ++s) {
            const bf16x8 a = *(const bf16x8*)&As[wm + frow][s * 32 + q8];
#pragma unroll
            for (int nf = 0; nf < 4; ++nf) {
                const bf16x8 bb = *(const bf16x8*)&Bs[nf * 16 + frow][s * 32 + q8];
                acc[nf] = __builtin_amdgcn_mfma_f32_16x16x32_bf16(a, bb, acc[nf], 0, 0, 0);
            }
        }
    }

    // D mapping: col=lane&15 (n), row=(lane>>4)*4+reg (m)
    const int col = lane & 15;
    const int rq  = (lane >> 4) * 4;
    const int m0  = mbase + wm + rq;
    const bool isA = sel == 0;            // block-uniform
#pragma unroll
    for (int nf = 0; nf < 4; ++nf) {
        const int nn = (nrow + nf * 16 + col);
        if (isA) {
            const float bb = b1[nn];
#pragma unroll
            for (int r = 0; r < 4; ++r)
                Ea[(m0 + r) * HH + nn] = __builtin_amdgcn_exp2f(C_EXP * (acc[nf][r] + bb));
        } else {
#pragma unroll
            for (int r = 0; r < 4; ++r)
                Eb[(m0 + r) * HH + nn] = __builtin_amdgcn_exp2f(C_EXP * acc[nf][r]);
        }
    }
}

// ---------------------------------------------------------------------------
// Kernel 2: triangular pairwise contraction. R14 structure with ALL FOUR
// tiles padded to stride 68 (R12's proven 0-conflict layout): tx-reads at
// (17*tx + h4)%8 bank-groups -> 2-way = free; ty-reads at 4 distinct groups
// (ty*4 offset) -> conflict-free; staged float4 writes <=2-way = free.
// Keeps R13 wins: W2 via wave-uniform scalar loads; jj-packed f32x2 accs.
// LDS = 34816 B -> 4 blocks/CU.
// ---------------------------------------------------------------------------
__global__ __launch_bounds__(256, 4) void pair_kernel(
    const float* __restrict__ Ea, const float* __restrict__ Eb,
    const float* __restrict__ W2, float* __restrict__ pbuf, int slice)
{
    __shared__ float eaj[32][68];
    __shared__ float ebj[32][68];
    __shared__ float eai[32][68];
    __shared__ float ebi[32][68];

    const int tid = threadIdx.x;
    const int tx  = tid & 15;
    const int ty  = tid >> 4;         // 0..15

    int tt = blockIdx.x, bi = 0, rem = NT;          // triangular decode
    while (tt >= rem) { tt -= rem; --rem; ++bi; }
    const int bj    = bi + tt;
    const int ibase = bi * 32;
    const int jbase = bj * 32;
    const int k0    = blockIdx.y * slice;

    f32x2 aC0[2] = {}, aC1[2] = {};   // [ii], packed over jj
    const f32x2 one2 = {1.f, 1.f};

    for (int kb = 0; kb < slice; kb += 64) {
        if (kb) __syncthreads();
        {   // stage 4 tiles x 32 rows x 64 floats = 2048 float4, 8/thread
            int p = tid;
#pragma unroll
            for (int it = 0; it < 8; ++it, p += 256) {
                const int tile = p >> 9;             // compile-time per it
                const int row  = (p >> 4) & 31;
                const int c4   = p & 15;
                if (tile == 0) {
                    const float4 v = *(const float4*)&Ea[(jbase + row) * HH + k0 + kb + c4 * 4];
                    *(float4*)&eaj[row][c4 * 4] = v;
                } else if (tile == 1) {
                    const float4 v = *(const float4*)&Ea[(ibase + row) * HH + k0 + kb + c4 * 4];
                    *(float4*)&eai[row][c4 * 4] = v;
                } else if (tile == 2) {
                    const float4 v = *(const float4*)&Eb[(ibase + row) * HH + k0 + kb + c4 * 4];
                    *(float4*)&ebi[row][c4 * 4] = v;
                } else {
                    const float4 v = *(const float4*)&Eb[(jbase + row) * HH + k0 + kb + c4 * 4];
                    *(float4*)&ebj[row][c4 * 4] = v;
                }
            }
        }
        __syncthreads();

#pragma unroll 4
        for (int h4 = 0; h4 < 16; ++h4) {
            const float4 Aj0 = *(const float4*)&eaj[tx][h4 * 4];
            const float4 Aj1 = *(const float4*)&eaj[tx + 16][h4 * 4];
            const float4 Bj0 = *(const float4*)&ebj[tx][h4 * 4];
            const float4 Bj1 = *(const float4*)&ebj[tx + 16][h4 * 4];
            const float4 Ai0 = *(const float4*)&eai[ty][h4 * 4];
            const float4 Ai1 = *(const float4*)&eai[ty + 16][h4 * 4];
            const float4 Bi0 = *(const float4*)&ebi[ty][h4 * 4];
            const float4 Bi1 = *(const float4*)&ebi[ty + 16][h4 * 4];
            const float4 w0q = *(const float4*)&W2[k0 + kb + h4 * 4];      // uniform -> scalar
            const float4 w1q = *(const float4*)&W2[HH + k0 + kb + h4 * 4];

#define DO_H(AJ0v, AJ1v, BI0v, BI1v, AI0v, AI1v, BJ0v, BJ1v, W0s, W1s)        \
            {                                                                  \
                const f32x2 Aj = {AJ0v, AJ1v};                                 \
                const f32x2 Bj = {BJ0v, BJ1v};                                 \
                const f32x2 d0 = __builtin_elementwise_fma((f32x2){BI0v, BI0v}, Aj, one2); \
                const f32x2 d1 = __builtin_elementwise_fma((f32x2){BI1v, BI1v}, Aj, one2); \
                const f32x2 e0 = __builtin_elementwise_fma((f32x2){AI0v, AI0v}, Bj, one2); \
                const f32x2 e1 = __builtin_elementwise_fma((f32x2){AI1v, AI1v}, Bj, one2); \
                const float dp0 = d0.x * d0.y, dp1 = d1.x * d1.y;              \
                const float ep0 = e0.x * e0.y, ep1 = e1.x * e1.y;              \
                const float DR = __builtin_amdgcn_rcpf(dp0 * dp1);             \
                const float ER = __builtin_amdgcn_rcpf(ep0 * ep1);             \
                const f32x2 dq = (f32x2){DR, DR} * (f32x2){dp1, dp0};          \
                const f32x2 eq = (f32x2){ER, ER} * (f32x2){ep1, ep0};          \
                const f32x2 u0 = (f32x2){dq.x, dq.x} * d0.yx + (f32x2){eq.x, eq.x} * e0.yx; \
                const f32x2 u1 = (f32x2){dq.y, dq.y} * d1.yx + (f32x2){eq.y, eq.y} * e1.yx; \
                aC0[0] = __builtin_elementwise_fma(u0, (f32x2){(W0s), (W0s)}, aC0[0]); \
                aC1[0] = __builtin_elementwise_fma(u0, (f32x2){(W1s), (W1s)}, aC1[0]); \
                aC0[1] = __builtin_elementwise_fma(u1, (f32x2){(W0s), (W0s)}, aC0[1]); \
                aC1[1] = __builtin_elementwise_fma(u1, (f32x2){(W1s), (W1s)}, aC1[1]); \
            }
            DO_H(Aj0.x, Aj1.x, Bi0.x, Bi1.x, Ai0.x, Ai1.x, Bj0.x, Bj1.x, w0q.x, w1q.x)
            DO_H(Aj0.y, Aj1.y, Bi0.y, Bi1.y, Ai0.y, Ai1.y, Bj0.y, Bj1.y, w0q.y, w1q.y)
            DO_H(Aj0.z, Aj1.z, Bi0.z, Bi1.z, Ai0.z, Ai1.z, Bj0.z, Bj1.z, w0q.z, w1q.z)
            DO_H(Aj0.w, Aj1.w, Bi0.w, Bi1.w, Ai0.w, Ai1.w, Bj0.w, Bj1.w, w0q.w, w1q.w)
#undef DO_H
        }
    }

    // value(ii,jj,c) = (c ? aC1 : aC0)[ii][jj]
    float* pb = pbuf + ((size_t)blockIdx.y * NTRI + blockIdx.x) * 2048;
#pragma unroll
    for (int ii = 0; ii < 2; ++ii)
#pragma unroll
        for (int jj = 0; jj < 2; ++jj) {
            const int li = ty + ii * 16, lj = tx + jj * 16;
            const f32x2 v = { jj ? aC0[ii].y : aC0[ii].x,
                              jj ? aC1[ii].y : aC1[ii].x };
            *(f32x2*)&pb[(li * 32 + lj) * 2] = v;
        }
}

// ---------------------------------------------------------------------------
// Kernel 3: combine: out = wsum[c]+b2[c] - sum_z pbuf; scatter (i,j)+(j,i).
// 1088 blocks, 2-way ILP on z.
// ---------------------------------------------------------------------------
__global__ __launch_bounds__(256) void combine_kernel(
    const float* __restrict__ pbuf, const float* __restrict__ W2,
    const float* __restrict__ b2, float* __restrict__ out, int nz)
{
    __shared__ float s_ws[2];

    const int tid = threadIdx.x;
    if (tid < 128) {
        const int c = tid >> 6, l = tid & 63;
        float s = 0.f;
#pragma unroll
        for (int q = 0; q < 4; ++q) {
            const float4 v = *(const float4*)&W2[c * HH + (l + q * 64) * 4];
            s += v.x + v.y + v.z + v.w;
        }
#pragma unroll
        for (int off = 32; off; off >>= 1) s += __shfl_down(s, off, 64);
        if (l == 0) s_ws[c] = s + b2[c];
    }
    __syncthreads();

    const int idx   = blockIdx.x * 256 + tid;   // 0 .. 136*2048-1
    const int t     = idx >> 11;                // block-uniform
    const int local = idx & 2047;
    int tt = t, bi = 0, rem = NT;
    while (tt >= rem) { tt -= rem; --rem; ++bi; }
    const int bj = bi + tt;

    float s0 = 0.f, s1 = 0.f;
    for (int z = 0; z < nz; z += 2) {   // nz is even
        s0 += pbuf[((size_t)z * NTRI + t) * 2048 + local];
        s1 += pbuf[((size_t)(z + 1) * NTRI + t) * 2048 + local];
    }
    const float s = s0 + s1;

    const int li = local >> 6;
    const int lj = (local >> 1) & 31;
    const int c  = local & 1;
    const float v = s_ws[c] - s;

    const int i = bi * 32 + li;
    const int j = bj * 32 + lj;
    out[(i * LL + j) * 2 + c] = v;
    out[(j * LL + i) * 2 + c] = v;   // diagonal tiles: same-value rewrite, benign
}

extern "C" void kernel_launch(void* const* d_in, const int* in_sizes, int n_in,
                              void* d_out, int out_size, void* d_ws, size_t ws_size,
                              hipStream_t stream)
{
    const float* lm = (const float*)d_in[0];
    const float* W1 = (const float*)d_in[1];
    const float* b1 = (const float*)d_in[2];
    const float* W2 = (const float*)d_in[3];
    const float* b2 = (const float*)d_in[4];
    float* out = (float*)d_out;

    char* ws = (char*)d_ws;
    float* Ea   = (float*)ws;                            // 2 MB
    float* Eb   = (float*)(ws + (2u << 20));             // 2 MB
    float* pbuf = (float*)(ws + (4u << 20) + 64);        // nz * 1.11 MB

    const size_t ubase = (4u << 20) + 64;
    const size_t pb16  = (size_t)16 * NTRI * 2048 * 4;   // 17.8 MB
    const int nz = (ws_size >= ubase + pb16) ? 16 : 8;   // ws_size const/session
    const int slice = HH / nz;

    proj_mfma_kernel<<<256, 256, 0, stream>>>(lm, W1, b1, Ea, Eb);
    pair_kernel<<<dim3(NTRI, nz), 256, 0, stream>>>(Ea, Eb, W2, pbuf, slice);
    combine_kernel<<<(NTRI * 2048) / 256, 256, 0, stream>>>(pbuf, W2, b2, out, nz);
}